// Round 6
// baseline (352.283 us; speedup 1.0000x reference)
//
#include <hip/hip_runtime.h>
#include <math.h>

#define T_TOK 16384
#define DIM   2048
#define NE    64
#define NACT  8
#define ALPHA 1e-4f
#define EPSV  1e-9f
#define TAU   2.5e-4f

typedef __attribute__((ext_vector_type(8))) short bf16x8;
typedef __attribute__((ext_vector_type(4))) float f32x4;

// RNE float->bf16 (values finite/small; no nan handling needed)
__device__ inline unsigned short bf16_rne(float f) {
    unsigned b = __float_as_uint(f);
    unsigned r = b + 0x7FFFu + ((b >> 16) & 1u);
    return (unsigned short)(r >> 16);
}

// ---------------------------------------------------------------------------
// prep: convert W (fp32, 64x2048) into FRAGMENT-MAJOR bf16 hi/lo buffers so
// that main_k's W-fragment load is one lane-contiguous 1KB read (L2-hot).
// Fragment index (st 0..63, j 0..3, lane 0..63): lane=(q<<4)|c15 holds
// W[e=16j+c15][k = st*32 + q*4 + (i<4 ? i : 12+i)] for slots i=0..7
// (same k-permutation as the HW-verified R7 kernel: x slots 0-3 = k0..k0+3,
// slots 4-7 = k0+16..k0+19). Also zeroes the 130 accumulator scalars
// (gP[64], gC[64], cntp, done) — replaces zero_k; Aout needs no zeroing
// anymore since main_k writes it with plain stores.
// ---------------------------------------------------------------------------
__global__ __launch_bounds__(256) void prep_k(
        const float* __restrict__ W,
        unsigned short* __restrict__ Wfh,
        unsigned short* __restrict__ Wfl,
        float* __restrict__ gz) {
    const int gid = blockIdx.x * 256 + threadIdx.x;   // 16384 fragments
    const int lane = gid & 63;
    const int j    = (gid >> 6) & 3;
    const int st   = gid >> 8;
    const int c15  = lane & 15;
    const int q    = lane >> 4;
    const int e    = 16 * j + c15;
    const int k0   = st * 32 + q * 4;

    const float* wr = W + (size_t)e * DIM + k0;
    const float4 v0 = *(const float4*)(wr);
    const float4 v1 = *(const float4*)(wr + 16);
    const float f[8] = {v0.x, v0.y, v0.z, v0.w, v1.x, v1.y, v1.z, v1.w};

    unsigned short hp[8], lp[8];
#pragma unroll
    for (int i = 0; i < 8; ++i) {
        const unsigned bb = __float_as_uint(f[i]);
        const unsigned hb = bb & 0xFFFF0000u;
        hp[i] = (unsigned short)(hb >> 16);
        lp[i] = bf16_rne(f[i] - __uint_as_float(hb));
    }
    unsigned short* dh = Wfh + (size_t)gid * 8;
    unsigned short* dl = Wfl + (size_t)gid * 8;
    *(ushort4*)(dh)     = *(const ushort4*)(hp);
    *(ushort4*)(dh + 4) = *(const ushort4*)(hp + 4);
    *(ushort4*)(dl)     = *(const ushort4*)(lp);
    *(ushort4*)(dl + 4) = *(const ushort4*)(lp + 4);

    if (gid < 130) gz[gid] = 0.0f;
}

// ---------------------------------------------------------------------------
// main: fused GEMM + gate. 256 blocks x 256 thr (4 waves); wave owns 16
// tokens x 64 experts x FULL K=2048 -> acc stays in registers (no k-split,
// no atomics, no zeroed accumulator). x via R7's 64B-segment pattern; W via
// fragment-major global loads (1KB lane-contiguous, L2-resident 512KB).
// bf16x3 MFMA (hi*hi + hi*lo + lo*hi), 16x16x32, layouts m89/m120-verified.
// K loop: 64 groups of 32 k = 2-deep pipeline, 31 iterations x 2 + 2 tail
// (R8 BUG FIX: was 15 iterations -> only K=1024 accumulated).
// Epilogue: transpose logits through LDS, then gate_k's verified rank-based
// top-8 / normalization / near-tie marking / loss partials, plus plain
// coalesced store of logits to Aout for fix_k.
// ---------------------------------------------------------------------------
__global__ __launch_bounds__(256) void main_k(
        const float* __restrict__ x,
        const unsigned short* __restrict__ Wfh,
        const unsigned short* __restrict__ Wfl,
        const float* __restrict__ bias,
        float* __restrict__ Aout,
        float* __restrict__ gates,
        float* __restrict__ idxf,
        float* __restrict__ gP,
        float* __restrict__ gC,
        int*   __restrict__ cntp,
        int*   __restrict__ list) {
    __shared__ __align__(16) float aff[4][16 * 68];   // per-wave logits (t x expert)
    __shared__ __align__(16) float sS[4][64];
    __shared__ __align__(16) float bS[4][64];
    __shared__ __align__(16) float bA[4][64];
    __shared__ float Pl[NE];
    __shared__ float Cl[NE];

    const int tid  = threadIdx.x;
    const int wv   = tid >> 6;
    const int lane = tid & 63;
    const int c15  = lane & 15;
    const int q    = lane >> 4;
    const int tw   = blockIdx.x * 64 + wv * 16;       // wave's first token

    if (tid < NE) { Pl[tid] = 0.0f; Cl[tid] = 0.0f; }

    // ---- K loop: full 2048 k, 64 groups of 32 ----
    const float* xc = x + (size_t)(tw + c15) * DIM + q * 4;
    const unsigned short* whc = Wfh + (size_t)lane * 8;
    const unsigned short* wlc = Wfl + (size_t)lane * 8;

    f32x4 acc[4];
#pragma unroll
    for (int j = 0; j < 4; ++j) acc[j] = (f32x4){0.f, 0.f, 0.f, 0.f};

    float4 ra[2][2];
    bf16x8 rh[2][4], rl[2][4];

#define LOADSTEP(s) {                                                     \
        ra[s][0] = *(const float4*)(xc + (s) * 32);                       \
        ra[s][1] = *(const float4*)(xc + (s) * 32 + 16);                  \
        _Pragma("unroll")                                                 \
        for (int j = 0; j < 4; ++j) {                                     \
            rh[s][j] = *(const bf16x8*)(whc + (s) * 2048 + j * 512);      \
            rl[s][j] = *(const bf16x8*)(wlc + (s) * 2048 + j * 512);      \
        }                                                                 \
    }

#define COMPSTEP(s) {                                                     \
        bf16x8 ah, al;                                                    \
        {                                                                 \
            float f[8] = {ra[s][0].x, ra[s][0].y, ra[s][0].z, ra[s][0].w, \
                          ra[s][1].x, ra[s][1].y, ra[s][1].z, ra[s][1].w};\
            _Pragma("unroll")                                             \
            for (int i = 0; i < 8; ++i) {                                 \
                const unsigned bb = __float_as_uint(f[i]);                \
                const unsigned hb = bb & 0xFFFF0000u;                     \
                ah[i] = (short)(hb >> 16);                                \
                al[i] = (short)bf16_rne(f[i] - __uint_as_float(hb));      \
            }                                                             \
        }                                                                 \
        _Pragma("unroll")                                                 \
        for (int j = 0; j < 4; ++j) {                                     \
            acc[j] = __builtin_amdgcn_mfma_f32_16x16x32_bf16(ah, rh[s][j], acc[j], 0, 0, 0); \
            acc[j] = __builtin_amdgcn_mfma_f32_16x16x32_bf16(ah, rl[s][j], acc[j], 0, 0, 0); \
            acc[j] = __builtin_amdgcn_mfma_f32_16x16x32_bf16(al, rh[s][j], acc[j], 0, 0, 0); \
        }                                                                 \
    }

    LOADSTEP(0);
    LOADSTEP(1);
#pragma unroll 3
    for (int p = 0; p < 31; ++p) {
        COMPSTEP(0);                       // group 2p
        xc  += 64;                         // advance 2 groups
        whc += 4096;
        wlc += 4096;
        LOADSTEP(0);                       // group 2p+2
        COMPSTEP(1);                       // group 2p+1
        LOADSTEP(1);                       // group 2p+3
    }
    COMPSTEP(0);                           // group 62
    COMPSTEP(1);                           // group 63
#undef LOADSTEP
#undef COMPSTEP

    // ---- transpose logits into LDS: C row=q*4+r (token), col=16j+c15 ----
#pragma unroll
    for (int j = 0; j < 4; ++j)
#pragma unroll
        for (int r = 0; r < 4; ++r)
            aff[wv][(q * 4 + r) * 68 + 16 * j + c15] = acc[j][r];
    __syncthreads();

    // ---- gate: 16 tokens per wave, lane = expert ----
    const float b = bias[lane];
    float pacc = 0.0f;
    float cacc = 0.0f;

    for (int t = 0; t < 16; ++t) {
        const int gt = tw + t;
        const float lg = aff[wv][t * 68 + lane];
        Aout[(size_t)gt * NE + lane] = lg;            // logits for fix_k
        const float a = 1.0f / (1.0f + expf(-lg));

        float rs = a;
#pragma unroll
        for (int off = 32; off; off >>= 1) rs += __shfl_xor(rs, off, 64);
        pacc += a / (rs + EPSV);

        const float s = a + b;
        sS[wv][lane] = s;
        __syncthreads();

        int rank = 0;
#pragma unroll
        for (int j4 = 0; j4 < 16; ++j4) {
            const float4 sv = *(const float4*)&sS[wv][j4 * 4];
            rank += (sv.x > s || (sv.x == s && (j4 * 4 + 0) < lane));
            rank += (sv.y > s || (sv.y == s && (j4 * 4 + 1) < lane));
            rank += (sv.z > s || (sv.z == s && (j4 * 4 + 2) < lane));
            rank += (sv.w > s || (sv.w == s && (j4 * 4 + 3) < lane));
        }
        bS[wv][rank] = s;
        bA[wv][rank] = a;
        __syncthreads();

        // marking: min adjacent gap among sorted ranks 0..8
        const float4 p0 = *(const float4*)&bS[wv][0];
        const float4 p1 = *(const float4*)&bS[wv][4];
        const float v8v = bS[wv][8];
        float gmin = p0.x - p0.y;
        gmin = fminf(gmin, p0.y - p0.z);
        gmin = fminf(gmin, p0.z - p0.w);
        gmin = fminf(gmin, p0.w - p1.x);
        gmin = fminf(gmin, p1.x - p1.y);
        gmin = fminf(gmin, p1.y - p1.z);
        gmin = fminf(gmin, p1.z - p1.w);
        gmin = fminf(gmin, p1.w - v8v);
        const bool marked = (gmin < TAU);

        const float4 a0 = *(const float4*)&bA[wv][0];
        const float4 a1 = *(const float4*)&bA[wv][4];
        const float gsum = ((((((a0.x + a0.y) + a0.z) + a0.w) + a1.x) + a1.y) + a1.z) + a1.w;
        const float inv = 1.0f / (gsum + EPSV);

        if (rank < NACT) {
            gates[(size_t)gt * NACT + rank] = a * inv;
            idxf [(size_t)gt * NACT + rank] = (float)lane;
            if (!marked) cacc += 1.0f;
        }
        if (lane == 0 && marked) {
            const int slot = atomicAdd(cntp, 1);
            list[slot] = gt;
        }
        __syncthreads();
    }

    atomicAdd(&Pl[lane], pacc);
    atomicAdd(&Cl[lane], cacc);
    __syncthreads();
    if (tid < NE) {
        atomicAdd(&gP[tid], Pl[tid]);
        atomicAdd(&gC[tid], Cl[tid]);
    }
}

// ---------------------------------------------------------------------------
// Fixup + loss: fp64 recompute of near-tie chain candidates (grid-strided,
// 2048 one-wave blocks), rank-based selection, then last-done block computes
// the balance loss. Unchanged from the verified R6/R7 version.
// ---------------------------------------------------------------------------
__global__ __launch_bounds__(64) void fix_k(
        const float* __restrict__ x,
        const float* __restrict__ Wg,
        const float* __restrict__ bias,
        const float* __restrict__ Aout,
        float* __restrict__ gates,
        float* __restrict__ idxf,
        const float* __restrict__ gP,
        float* __restrict__ gC,
        const int* __restrict__ cntp,
        int*   __restrict__ done,
        const int* __restrict__ list,
        float* __restrict__ lossOut) {
    __shared__ __align__(16) float  sS[64];
    __shared__ __align__(16) float  bS[64];
    __shared__ __align__(16) int    bI[64];
    __shared__ __align__(16) double dS[64];
    __shared__ __align__(16) double dR[64];

    const int lane = threadIdx.x;
    const int cnt = *cntp;
    float cacc = 0.0f;

    for (int idx = blockIdx.x; idx < cnt; idx += gridDim.x) {
        const int t = list[idx];
        const float lg  = Aout[(size_t)t * NE + lane];
        const float a32 = 1.0f / (1.0f + expf(-lg));   // same expr as main_k
        const float bl  = bias[lane];
        const float s32 = a32 + bl;

        // hoist x row: k = 4*lane + 256*m
        const float* xr = x + (size_t)t * DIM;
        float4 xv[8];
#pragma unroll
        for (int m = 0; m < 8; ++m) xv[m] = *(const float4*)(xr + 4 * lane + 256 * m);

        sS[lane] = s32;
        __syncthreads();
        int rank = 0;
#pragma unroll
        for (int j4 = 0; j4 < 16; ++j4) {
            const float4 sv = *(const float4*)&sS[j4 * 4];
            rank += (sv.x > s32 || (sv.x == s32 && (j4 * 4 + 0) < lane));
            rank += (sv.y > s32 || (sv.y == s32 && (j4 * 4 + 1) < lane));
            rank += (sv.z > s32 || (sv.z == s32 && (j4 * 4 + 2) < lane));
            rank += (sv.w > s32 || (sv.w == s32 && (j4 * 4 + 3) < lane));
        }
        bS[rank] = s32;
        bI[rank] = lane;
        __syncthreads();

        // sorted top-16 + chain closure touching ranks 0..8
        float vr[16];
        int   ir[16];
#pragma unroll
        for (int k4 = 0; k4 < 4; ++k4) {
            const float4 vv = *(const float4*)&bS[k4 * 4];
            const int4   ii = *(const int4*)&bI[k4 * 4];
            vr[k4 * 4 + 0] = vv.x; vr[k4 * 4 + 1] = vv.y;
            vr[k4 * 4 + 2] = vv.z; vr[k4 * 4 + 3] = vv.w;
            ir[k4 * 4 + 0] = ii.x; ir[k4 * 4 + 1] = ii.y;
            ir[k4 * 4 + 2] = ii.z; ir[k4 * 4 + 3] = ii.w;
        }
        bool needs[16];
#pragma unroll
        for (int k = 0; k < 16; ++k) needs[k] = false;
#pragma unroll
        for (int k = 1; k <= 8; ++k)
            if (vr[k - 1] - vr[k] < TAU) { needs[k - 1] = true; needs[k] = true; }
#pragma unroll
        for (int k = 9; k < 16; ++k)
            if (needs[k - 1] && (vr[k - 1] - vr[k] < TAU)) needs[k] = true;

        unsigned long long mb = 0ull;
#pragma unroll
        for (int k = 0; k < 16; ++k)
            if (needs[k]) mb |= (1ull << ir[k]);

        // fp64 recompute of candidates, two at a time
        double ad = (double)a32;
        while (mb) {
            const int e0 = __ffsll(mb) - 1;
            mb &= mb - 1;
            int e1 = -1;
            if (mb) { e1 = __ffsll(mb) - 1; mb &= mb - 1; }
            const float* wr0 = Wg + (size_t)e0 * DIM;
            const float* wr1 = Wg + (size_t)((e1 >= 0) ? e1 : e0) * DIM;
            float4 w0[8], w1[8];
#pragma unroll
            for (int m = 0; m < 8; ++m) {
                w0[m] = *(const float4*)(wr0 + 4 * lane + 256 * m);
                w1[m] = *(const float4*)(wr1 + 4 * lane + 256 * m);
            }
            double z0 = 0.0, z1 = 0.0;
#pragma unroll
            for (int m = 0; m < 8; ++m) {
                z0 = fma((double)xv[m].x, (double)w0[m].x, z0);
                z0 = fma((double)xv[m].y, (double)w0[m].y, z0);
                z0 = fma((double)xv[m].z, (double)w0[m].z, z0);
                z0 = fma((double)xv[m].w, (double)w0[m].w, z0);
                z1 = fma((double)xv[m].x, (double)w1[m].x, z1);
                z1 = fma((double)xv[m].y, (double)w1[m].y, z1);
                z1 = fma((double)xv[m].z, (double)w1[m].z, z1);
                z1 = fma((double)xv[m].w, (double)w1[m].w, z1);
            }
#pragma unroll
            for (int off = 32; off; off >>= 1) {
                z0 += __shfl_xor(z0, off, 64);
                z1 += __shfl_xor(z1, off, 64);
            }
            const double af0 = 1.0 / (1.0 + exp(-z0));
            if (lane == e0) ad = af0;
            if (e1 >= 0) {
                const double af1 = 1.0 / (1.0 + exp(-z1));
                if (lane == e1) ad = af1;
            }
        }

        // final fp64 rank-based top-8
        const double sd = ad + (double)bl;
        dS[lane] = sd;
        __syncthreads();
        int r2 = 0;
#pragma unroll
        for (int j2 = 0; j2 < 32; ++j2) {
            const double2 dv = *(const double2*)&dS[j2 * 2];
            r2 += (dv.x > sd || (dv.x == sd && (2 * j2 + 0) < lane));
            r2 += (dv.y > sd || (dv.y == sd && (2 * j2 + 1) < lane));
        }
        dR[r2] = ad;
        __syncthreads();
        const double2 g0 = *(const double2*)&dR[0];
        const double2 g1 = *(const double2*)&dR[2];
        const double2 g2 = *(const double2*)&dR[4];
        const double2 g3 = *(const double2*)&dR[6];
        const double gsum = ((((((g0.x + g0.y) + g1.x) + g1.y) + g2.x) + g2.y) + g3.x) + g3.y;
        const double inv = 1.0 / (gsum + (double)EPSV);

        if (r2 < NACT) {
            gates[(size_t)t * NACT + r2] = (float)(ad * inv);
            idxf [(size_t)t * NACT + r2] = (float)lane;
            cacc += 1.0f;
        }
        __syncthreads();
    }

    atomicAdd(&gC[lane], cacc);
    __threadfence();
    int tk = 0;
    if (lane == 0) tk = atomicAdd(done, 1);
    tk = __shfl(tk, 0, 64);
    if (tk == (int)gridDim.x - 1) {
        __threadfence();
        const float f = gC[lane] * ((float)NE / (float)(NACT * T_TOK));
        const float P = gP[lane] / (float)T_TOK;
        float v = f * P;
#pragma unroll
        for (int off = 32; off; off >>= 1) v += __shfl_xor(v, off, 64);
        if (lane == 0) lossOut[0] = ALPHA * v;
    }
}

extern "C" void kernel_launch(void* const* d_in, const int* in_sizes, int n_in,
                              void* d_out, int out_size, void* d_ws, size_t ws_size,
                              hipStream_t stream) {
    const float* x    = (const float*)d_in[0];
    const float* Wg   = (const float*)d_in[1];
    const float* bias = (const float*)d_in[2];
    float* out = (float*)d_out;
    float* gates = out;
    float* idxf  = out + (size_t)T_TOK * NACT;
    float* loss  = out + 2 * (size_t)T_TOK * NACT;

    // workspace layout (16B-aligned sections):
    //   [0, 4MB)        Aout logits
    //   [4MB, 4.25MB)   Wf_hi (bf16 fragment-major)
    //   [4.25MB, 4.5MB) Wf_lo
    //   [4.5MB, ...)    gP[64], gC[64], cntp, done, list[16384]
    float* Aout = (float*)d_ws;
    unsigned short* Wfh = (unsigned short*)((char*)d_ws + (4u << 20));
    unsigned short* Wfl = (unsigned short*)((char*)d_ws + (4u << 20) + (256u << 10));
    float* gP   = (float*)((char*)d_ws + (4u << 20) + (512u << 10));
    float* gC   = gP + NE;
    int*   cntp = (int*)(gC + NE);
    int*   done = cntp + 1;
    int*   list = done + 1;

    prep_k<<<64, 256, 0, stream>>>(Wg, Wfh, Wfl, gP);
    main_k<<<256, 256, 0, stream>>>(x, Wfh, Wfl, bias, Aout, gates, idxf,
                                    gP, gC, cntp, list);
    fix_k<<<2048, 64, 0, stream>>>(x, Wg, bias, Aout, gates, idxf,
                                   gP, gC, cntp, done, list, loss);
}

// Round 9
// 323.866 us; speedup vs baseline: 1.0877x; 1.0877x over previous
//
#include <hip/hip_runtime.h>
#include <math.h>

#define T_TOK 16384
#define DIM   2048
#define NE    64
#define NACT  8
#define ALPHA 1e-4f
#define EPSV  1e-9f
#define TAU   2.5e-4f

typedef __attribute__((ext_vector_type(8))) short bf16x8;
typedef __attribute__((ext_vector_type(4))) float f32x4;

// RNE float->bf16 (values finite/small; no nan handling needed)
__device__ inline unsigned short bf16_rne(float f) {
    unsigned b = __float_as_uint(f);
    unsigned r = b + 0x7FFFu + ((b >> 16) & 1u);
    return (unsigned short)(r >> 16);
}

// ---------------------------------------------------------------------------
// prep: convert W (fp32, 64x2048) into FRAGMENT-MAJOR bf16 hi/lo buffers so
// that main_k's W-fragment load is one lane-contiguous 1KB read (L2-hot).
// Fragment index (st 0..63, j 0..3, lane 0..63): lane=(q<<4)|c15 holds
// W[e=16j+c15][k = st*32 + q*4 + (i<4 ? i : 12+i)] for slots i=0..7
// (same k-permutation as the HW-verified R7 kernel). Also zeroes the 130
// accumulator scalars (gP[64], gC[64], cntp, done).
// ---------------------------------------------------------------------------
__global__ __launch_bounds__(256) void prep_k(
        const float* __restrict__ W,
        unsigned short* __restrict__ Wfh,
        unsigned short* __restrict__ Wfl,
        float* __restrict__ gz) {
    const int gid = blockIdx.x * 256 + threadIdx.x;   // 16384 fragments
    const int lane = gid & 63;
    const int j    = (gid >> 6) & 3;
    const int st   = gid >> 8;
    const int c15  = lane & 15;
    const int q    = lane >> 4;
    const int e    = 16 * j + c15;
    const int k0   = st * 32 + q * 4;

    const float* wr = W + (size_t)e * DIM + k0;
    const float4 v0 = *(const float4*)(wr);
    const float4 v1 = *(const float4*)(wr + 16);
    const float f[8] = {v0.x, v0.y, v0.z, v0.w, v1.x, v1.y, v1.z, v1.w};

    unsigned short hp[8], lp[8];
#pragma unroll
    for (int i = 0; i < 8; ++i) {
        const unsigned bb = __float_as_uint(f[i]);
        const unsigned hb = bb & 0xFFFF0000u;
        hp[i] = (unsigned short)(hb >> 16);
        lp[i] = bf16_rne(f[i] - __uint_as_float(hb));
    }
    unsigned short* dh = Wfh + (size_t)gid * 8;
    unsigned short* dl = Wfl + (size_t)gid * 8;
    *(ushort4*)(dh)     = *(const ushort4*)(hp);
    *(ushort4*)(dh + 4) = *(const ushort4*)(hp + 4);
    *(ushort4*)(dl)     = *(const ushort4*)(lp);
    *(ushort4*)(dl + 4) = *(const ushort4*)(lp + 4);

    if (gid < 130) gz[gid] = 0.0f;
}

// ---------------------------------------------------------------------------
// main: fused GEMM + gate, R10: in-block K-SPLIT x4 (occupancy fix).
// R9's full-K-per-wave gave only 1024 waves total = 1 wave/SIMD ->
// latency-bound at 11.5% occupancy (MfmaUtil 2.8, VALU 9.8, HBM 5.3 -- all
// idle). Now: block = 256 thr (4 waves) owns 16 TOKENS; wave wv computes
// K-quarter [wv*512, wv*512+512) (16 groups of 32), writes partial 16x64
// logits to affp[wv] in LDS, barrier, then the 4 waves sum partials and run
// the verified gate (4 tokens each). Grid 1024 blocks -> 4096 waves
// (~20/CU, VGPR-capped) = R7-gemm occupancy, with no global atomics and no
// separate gate pass. bf16x3 MFMA 16x16x32 (layouts m89/m120-verified).
// ---------------------------------------------------------------------------
__global__ __launch_bounds__(256) void main_k(
        const float* __restrict__ x,
        const unsigned short* __restrict__ Wfh,
        const unsigned short* __restrict__ Wfl,
        const float* __restrict__ bias,
        float* __restrict__ Aout,
        float* __restrict__ gates,
        float* __restrict__ idxf,
        float* __restrict__ gP,
        float* __restrict__ gC,
        int*   __restrict__ cntp,
        int*   __restrict__ list) {
    __shared__ __align__(16) float affp[4][16 * 68];  // per-k-quarter partial logits
    __shared__ __align__(16) float sS[4][64];
    __shared__ __align__(16) float bS[4][64];
    __shared__ __align__(16) float bA[4][64];
    __shared__ float Pl[NE];
    __shared__ float Cl[NE];

    const int tid  = threadIdx.x;
    const int wv   = tid >> 6;       // k-quarter 0..3
    const int lane = tid & 63;
    const int c15  = lane & 15;
    const int q    = lane >> 4;
    const int tokBase = blockIdx.x * 16;              // block's 16 tokens

    if (tid < NE) { Pl[tid] = 0.0f; Cl[tid] = 0.0f; }

    // ---- K loop: quarter = 16 groups of 32 k ----
    const float* xc = x + (size_t)(tokBase + c15) * DIM + wv * 512 + q * 4;
    const unsigned short* whc = Wfh + (size_t)(wv * 16) * 2048 + lane * 8;
    const unsigned short* wlc = Wfl + (size_t)(wv * 16) * 2048 + lane * 8;

    f32x4 acc[4];
#pragma unroll
    for (int j = 0; j < 4; ++j) acc[j] = (f32x4){0.f, 0.f, 0.f, 0.f};

    float4 ra[2][2];
    bf16x8 rh[2][4], rl[2][4];

#define LOADSTEP(s) {                                                     \
        ra[s][0] = *(const float4*)(xc + (s) * 32);                       \
        ra[s][1] = *(const float4*)(xc + (s) * 32 + 16);                  \
        _Pragma("unroll")                                                 \
        for (int j = 0; j < 4; ++j) {                                     \
            rh[s][j] = *(const bf16x8*)(whc + (s) * 2048 + j * 512);      \
            rl[s][j] = *(const bf16x8*)(wlc + (s) * 2048 + j * 512);      \
        }                                                                 \
    }

#define COMPSTEP(s) {                                                     \
        bf16x8 ah, al;                                                    \
        {                                                                 \
            float f[8] = {ra[s][0].x, ra[s][0].y, ra[s][0].z, ra[s][0].w, \
                          ra[s][1].x, ra[s][1].y, ra[s][1].z, ra[s][1].w};\
            _Pragma("unroll")                                             \
            for (int i = 0; i < 8; ++i) {                                 \
                const unsigned bb = __float_as_uint(f[i]);                \
                const unsigned hb = bb & 0xFFFF0000u;                     \
                ah[i] = (short)(hb >> 16);                                \
                al[i] = (short)bf16_rne(f[i] - __uint_as_float(hb));      \
            }                                                             \
        }                                                                 \
        _Pragma("unroll")                                                 \
        for (int j = 0; j < 4; ++j) {                                     \
            acc[j] = __builtin_amdgcn_mfma_f32_16x16x32_bf16(ah, rh[s][j], acc[j], 0, 0, 0); \
            acc[j] = __builtin_amdgcn_mfma_f32_16x16x32_bf16(ah, rl[s][j], acc[j], 0, 0, 0); \
            acc[j] = __builtin_amdgcn_mfma_f32_16x16x32_bf16(al, rh[s][j], acc[j], 0, 0, 0); \
        }                                                                 \
    }

    LOADSTEP(0);
    LOADSTEP(1);
#pragma unroll
    for (int p = 0; p < 7; ++p) {
        COMPSTEP(0);                       // group 2p
        xc  += 64;                         // advance 2 groups
        whc += 4096;
        wlc += 4096;
        LOADSTEP(0);                       // group 2p+2
        COMPSTEP(1);                       // group 2p+1
        LOADSTEP(1);                       // group 2p+3
    }
    COMPSTEP(0);                           // group 14
    COMPSTEP(1);                           // group 15
#undef LOADSTEP
#undef COMPSTEP

    // ---- store k-partial logits: C row=q*4+r (token), col=16j+c15 ----
#pragma unroll
    for (int j = 0; j < 4; ++j)
#pragma unroll
        for (int r = 0; r < 4; ++r)
            affp[wv][(q * 4 + r) * 68 + 16 * j + c15] = acc[j][r];
    __syncthreads();

    // ---- gate: 4 tokens per wave (wave wv -> tokens wv*4..wv*4+3) ----
    const float b = bias[lane];
    float pacc = 0.0f;
    float cacc = 0.0f;

    for (int it = 0; it < 4; ++it) {
        const int t  = wv * 4 + it;
        const int gt = tokBase + t;
        const int o  = t * 68 + lane;
        const float lg = ((affp[0][o] + affp[1][o]) + affp[2][o]) + affp[3][o];
        Aout[(size_t)gt * NE + lane] = lg;            // logits for fix_k
        const float a = 1.0f / (1.0f + expf(-lg));

        float rs = a;
#pragma unroll
        for (int off = 32; off; off >>= 1) rs += __shfl_xor(rs, off, 64);
        pacc += a / (rs + EPSV);

        const float s = a + b;
        sS[wv][lane] = s;
        __syncthreads();

        int rank = 0;
#pragma unroll
        for (int j4 = 0; j4 < 16; ++j4) {
            const float4 sv = *(const float4*)&sS[wv][j4 * 4];
            rank += (sv.x > s || (sv.x == s && (j4 * 4 + 0) < lane));
            rank += (sv.y > s || (sv.y == s && (j4 * 4 + 1) < lane));
            rank += (sv.z > s || (sv.z == s && (j4 * 4 + 2) < lane));
            rank += (sv.w > s || (sv.w == s && (j4 * 4 + 3) < lane));
        }
        bS[wv][rank] = s;
        bA[wv][rank] = a;
        __syncthreads();

        // marking: min adjacent gap among sorted ranks 0..8
        const float4 p0 = *(const float4*)&bS[wv][0];
        const float4 p1 = *(const float4*)&bS[wv][4];
        const float v8v = bS[wv][8];
        float gmin = p0.x - p0.y;
        gmin = fminf(gmin, p0.y - p0.z);
        gmin = fminf(gmin, p0.z - p0.w);
        gmin = fminf(gmin, p0.w - p1.x);
        gmin = fminf(gmin, p1.x - p1.y);
        gmin = fminf(gmin, p1.y - p1.z);
        gmin = fminf(gmin, p1.z - p1.w);
        gmin = fminf(gmin, p1.w - v8v);
        const bool marked = (gmin < TAU);

        const float4 a0 = *(const float4*)&bA[wv][0];
        const float4 a1 = *(const float4*)&bA[wv][4];
        const float gsum = ((((((a0.x + a0.y) + a0.z) + a0.w) + a1.x) + a1.y) + a1.z) + a1.w;
        const float inv = 1.0f / (gsum + EPSV);

        if (rank < NACT) {
            gates[(size_t)gt * NACT + rank] = a * inv;
            idxf [(size_t)gt * NACT + rank] = (float)lane;
            if (!marked) cacc += 1.0f;
        }
        if (lane == 0 && marked) {
            const int slot = atomicAdd(cntp, 1);
            list[slot] = gt;
        }
        __syncthreads();
    }

    atomicAdd(&Pl[lane], pacc);
    atomicAdd(&Cl[lane], cacc);
    __syncthreads();
    if (tid < NE) {
        atomicAdd(&gP[tid], Pl[tid]);
        atomicAdd(&gC[tid], Cl[tid]);
    }
}

// ---------------------------------------------------------------------------
// Fixup + loss: fp64 recompute of near-tie chain candidates (grid-strided,
// 2048 one-wave blocks), rank-based selection, then last-done block computes
// the balance loss. Unchanged from the verified R6/R7 version.
// ---------------------------------------------------------------------------
__global__ __launch_bounds__(64) void fix_k(
        const float* __restrict__ x,
        const float* __restrict__ Wg,
        const float* __restrict__ bias,
        const float* __restrict__ Aout,
        float* __restrict__ gates,
        float* __restrict__ idxf,
        const float* __restrict__ gP,
        float* __restrict__ gC,
        const int* __restrict__ cntp,
        int*   __restrict__ done,
        const int* __restrict__ list,
        float* __restrict__ lossOut) {
    __shared__ __align__(16) float  sS[64];
    __shared__ __align__(16) float  bS[64];
    __shared__ __align__(16) int    bI[64];
    __shared__ __align__(16) double dS[64];
    __shared__ __align__(16) double dR[64];

    const int lane = threadIdx.x;
    const int cnt = *cntp;
    float cacc = 0.0f;

    for (int idx = blockIdx.x; idx < cnt; idx += gridDim.x) {
        const int t = list[idx];
        const float lg  = Aout[(size_t)t * NE + lane];
        const float a32 = 1.0f / (1.0f + expf(-lg));   // same expr as main_k
        const float bl  = bias[lane];
        const float s32 = a32 + bl;

        // hoist x row: k = 4*lane + 256*m
        const float* xr = x + (size_t)t * DIM;
        float4 xv[8];
#pragma unroll
        for (int m = 0; m < 8; ++m) xv[m] = *(const float4*)(xr + 4 * lane + 256 * m);

        sS[lane] = s32;
        __syncthreads();
        int rank = 0;
#pragma unroll
        for (int j4 = 0; j4 < 16; ++j4) {
            const float4 sv = *(const float4*)&sS[j4 * 4];
            rank += (sv.x > s32 || (sv.x == s32 && (j4 * 4 + 0) < lane));
            rank += (sv.y > s32 || (sv.y == s32 && (j4 * 4 + 1) < lane));
            rank += (sv.z > s32 || (sv.z == s32 && (j4 * 4 + 2) < lane));
            rank += (sv.w > s32 || (sv.w == s32 && (j4 * 4 + 3) < lane));
        }
        bS[rank] = s32;
        bI[rank] = lane;
        __syncthreads();

        // sorted top-16 + chain closure touching ranks 0..8
        float vr[16];
        int   ir[16];
#pragma unroll
        for (int k4 = 0; k4 < 4; ++k4) {
            const float4 vv = *(const float4*)&bS[k4 * 4];
            const int4   ii = *(const int4*)&bI[k4 * 4];
            vr[k4 * 4 + 0] = vv.x; vr[k4 * 4 + 1] = vv.y;
            vr[k4 * 4 + 2] = vv.z; vr[k4 * 4 + 3] = vv.w;
            ir[k4 * 4 + 0] = ii.x; ir[k4 * 4 + 1] = ii.y;
            ir[k4 * 4 + 2] = ii.z; ir[k4 * 4 + 3] = ii.w;
        }
        bool needs[16];
#pragma unroll
        for (int k = 0; k < 16; ++k) needs[k] = false;
#pragma unroll
        for (int k = 1; k <= 8; ++k)
            if (vr[k - 1] - vr[k] < TAU) { needs[k - 1] = true; needs[k] = true; }
#pragma unroll
        for (int k = 9; k < 16; ++k)
            if (needs[k - 1] && (vr[k - 1] - vr[k] < TAU)) needs[k] = true;

        unsigned long long mb = 0ull;
#pragma unroll
        for (int k = 0; k < 16; ++k)
            if (needs[k]) mb |= (1ull << ir[k]);

        // fp64 recompute of candidates, two at a time
        double ad = (double)a32;
        while (mb) {
            const int e0 = __ffsll(mb) - 1;
            mb &= mb - 1;
            int e1 = -1;
            if (mb) { e1 = __ffsll(mb) - 1; mb &= mb - 1; }
            const float* wr0 = Wg + (size_t)e0 * DIM;
            const float* wr1 = Wg + (size_t)((e1 >= 0) ? e1 : e0) * DIM;
            float4 w0[8], w1[8];
#pragma unroll
            for (int m = 0; m < 8; ++m) {
                w0[m] = *(const float4*)(wr0 + 4 * lane + 256 * m);
                w1[m] = *(const float4*)(wr1 + 4 * lane + 256 * m);
            }
            double z0 = 0.0, z1 = 0.0;
#pragma unroll
            for (int m = 0; m < 8; ++m) {
                z0 = fma((double)xv[m].x, (double)w0[m].x, z0);
                z0 = fma((double)xv[m].y, (double)w0[m].y, z0);
                z0 = fma((double)xv[m].z, (double)w0[m].z, z0);
                z0 = fma((double)xv[m].w, (double)w0[m].w, z0);
                z1 = fma((double)xv[m].x, (double)w1[m].x, z1);
                z1 = fma((double)xv[m].y, (double)w1[m].y, z1);
                z1 = fma((double)xv[m].z, (double)w1[m].z, z1);
                z1 = fma((double)xv[m].w, (double)w1[m].w, z1);
            }
#pragma unroll
            for (int off = 32; off; off >>= 1) {
                z0 += __shfl_xor(z0, off, 64);
                z1 += __shfl_xor(z1, off, 64);
            }
            const double af0 = 1.0 / (1.0 + exp(-z0));
            if (lane == e0) ad = af0;
            if (e1 >= 0) {
                const double af1 = 1.0 / (1.0 + exp(-z1));
                if (lane == e1) ad = af1;
            }
        }

        // final fp64 rank-based top-8
        const double sd = ad + (double)bl;
        dS[lane] = sd;
        __syncthreads();
        int r2 = 0;
#pragma unroll
        for (int j2 = 0; j2 < 32; ++j2) {
            const double2 dv = *(const double2*)&dS[j2 * 2];
            r2 += (dv.x > sd || (dv.x == sd && (2 * j2 + 0) < lane));
            r2 += (dv.y > sd || (dv.y == sd && (2 * j2 + 1) < lane));
        }
        dR[r2] = ad;
        __syncthreads();
        const double2 g0 = *(const double2*)&dR[0];
        const double2 g1 = *(const double2*)&dR[2];
        const double2 g2 = *(const double2*)&dR[4];
        const double2 g3 = *(const double2*)&dR[6];
        const double gsum = ((((((g0.x + g0.y) + g1.x) + g1.y) + g2.x) + g2.y) + g3.x) + g3.y;
        const double inv = 1.0 / (gsum + (double)EPSV);

        if (r2 < NACT) {
            gates[(size_t)t * NACT + r2] = (float)(ad * inv);
            idxf [(size_t)t * NACT + r2] = (float)lane;
            cacc += 1.0f;
        }
        __syncthreads();
    }

    atomicAdd(&gC[lane], cacc);
    __threadfence();
    int tk = 0;
    if (lane == 0) tk = atomicAdd(done, 1);
    tk = __shfl(tk, 0, 64);
    if (tk == (int)gridDim.x - 1) {
        __threadfence();
        const float f = gC[lane] * ((float)NE / (float)(NACT * T_TOK));
        const float P = gP[lane] / (float)T_TOK;
        float v = f * P;
#pragma unroll
        for (int off = 32; off; off >>= 1) v += __shfl_xor(v, off, 64);
        if (lane == 0) lossOut[0] = ALPHA * v;
    }
}

extern "C" void kernel_launch(void* const* d_in, const int* in_sizes, int n_in,
                              void* d_out, int out_size, void* d_ws, size_t ws_size,
                              hipStream_t stream) {
    const float* x    = (const float*)d_in[0];
    const float* Wg   = (const float*)d_in[1];
    const float* bias = (const float*)d_in[2];
    float* out = (float*)d_out;
    float* gates = out;
    float* idxf  = out + (size_t)T_TOK * NACT;
    float* loss  = out + 2 * (size_t)T_TOK * NACT;

    // workspace layout (16B-aligned sections):
    //   [0, 4MB)        Aout logits
    //   [4MB, 4.25MB)   Wf_hi (bf16 fragment-major)
    //   [4.25MB, 4.5MB) Wf_lo
    //   [4.5MB, ...)    gP[64], gC[64], cntp, done, list[16384]
    float* Aout = (float*)d_ws;
    unsigned short* Wfh = (unsigned short*)((char*)d_ws + (4u << 20));
    unsigned short* Wfl = (unsigned short*)((char*)d_ws + (4u << 20) + (256u << 10));
    float* gP   = (float*)((char*)d_ws + (4u << 20) + (512u << 10));
    float* gC   = gP + NE;
    int*   cntp = (int*)(gC + NE);
    int*   done = cntp + 1;
    int*   list = done + 1;

    prep_k<<<64, 256, 0, stream>>>(Wg, Wfh, Wfl, gP);
    main_k<<<T_TOK / 16, 256, 0, stream>>>(x, Wfh, Wfl, bias, Aout, gates, idxf,
                                           gP, gC, cntp, list);
    fix_k<<<2048, 64, 0, stream>>>(x, Wg, bias, Aout, gates, idxf,
                                   gP, gC, cntp, done, list, loss);
}